// Round 2
// baseline (1345.051 us; speedup 1.0000x reference)
//
#include <hip/hip_runtime.h>
#include <hip/hip_fp16.h>
#include <hip/hip_bf16.h>

// SlotAttention restructured:
//  dots = qs . x   with qs = LN(slots) @ (scale * Wq^T Wk)   (K never materialized)
//  updates = (N/wsum) * (sum_j w_j x_j) @ Wv^T               (V never materialized)
// x = LN(inputs) stored once as fp16. All accumulation fp32. Output fp32.

#define BB 64
#define NN 4096
#define DD 256
#define NSL 8
#define NITER 3

__device__ __forceinline__ float wredsum(float v){
#pragma unroll
  for(int m=32;m;m>>=1) v += __shfl_xor(v, m, 64);
  return v;
}
__device__ __forceinline__ float2 u2f2(unsigned u){ __half2 h; __builtin_memcpy(&h,&u,4); return __half22float2(h); }

// ---------------- prep: weight transposes + slots broadcast init ----------------
__global__ __launch_bounds__(256) void k_prep(
    const float* __restrict__ Wih, const float* __restrict__ Whh,
    const float* __restrict__ W1,  const float* __restrict__ W2,
    const float* __restrict__ Wv,  const float* __restrict__ sinit,
    float* __restrict__ WihT, float* __restrict__ WhhT,
    float* __restrict__ W1T,  float* __restrict__ W2T,
    float* __restrict__ WvT,  float* __restrict__ slots){
  for(int idx = blockIdx.x*256 + threadIdx.x; idx < 1114112; idx += gridDim.x*256){
    if(idx < 196608){ int d=idx>>8, c=idx&255; WihT[c*768+d] = Wih[idx]; }
    else if(idx < 393216){ int k=idx-196608; int d=k>>8,  c=k&255;  WhhT[c*768+d]  = Whh[k]; }
    else if(idx < 655360){ int k=idx-393216; int d=k>>8,  c=k&255;  W1T[c*1024+d]  = W1[k]; }   // W1 [1024][256]
    else if(idx < 917504){ int k=idx-655360; int d=k>>10, c=k&1023; W2T[c*256+d]   = W2[k]; }   // W2 [256][1024]
    else if(idx < 983040){ int k=idx-917504; int d=k>>8,  c=k&255;  WvT[c*256+d]   = Wv[k]; }
    else { int k=idx-983040; slots[k] = sinit[k&2047]; }                                        // broadcast over b
  }
}

// ---------------- M = scale * Wq^T @ Wk  (M[e][c]) ----------------
__global__ __launch_bounds__(256) void k_M(const float* __restrict__ Wq, const float* __restrict__ Wk,
                                           float* __restrict__ M){
  int e = blockIdx.x, c = threadIdx.x;
  float acc = 0.f;
#pragma unroll 4
  for(int d=0; d<256; d++) acc += Wq[d*256+e]*Wk[d*256+c];
  M[e*256+c] = acc * 0.0625f;  // 256^-0.5
}

// ---------------- x = LN(inputs) -> fp16 ----------------
__global__ __launch_bounds__(256) void k_ln_x(const float* __restrict__ in, const float* __restrict__ g,
                                              const float* __restrict__ bbv, __half* __restrict__ x){
  int row  = blockIdx.x*4 + (threadIdx.x>>6);
  int lane = threadIdx.x&63;
  const float4 v = ((const float4*)(in + (size_t)row*DD))[lane];
  float s  = v.x+v.y+v.z+v.w;
  float ss = v.x*v.x+v.y*v.y+v.z*v.z+v.w*v.w;
  s = wredsum(s); ss = wredsum(ss);
  float m = s*(1.0f/256.0f);
  float r = rsqrtf(ss*(1.0f/256.0f) - m*m + 1e-5f);
  float4 gv = ((const float4*)g)[lane];
  float4 bv = ((const float4*)bbv)[lane];
  float y0=(v.x-m)*r*gv.x+bv.x, y1=(v.y-m)*r*gv.y+bv.y;
  float y2=(v.z-m)*r*gv.z+bv.z, y3=(v.w-m)*r*gv.w+bv.w;
  __half2 h0=__floats2half2_rn(y0,y1), h1=__floats2half2_rn(y2,y3);
  uint2 u; __builtin_memcpy(&u.x,&h0,4); __builtin_memcpy(&u.y,&h1,4);
  ((uint2*)(x + (size_t)row*DD))[lane] = u;
}

// ---------------- per-iter: qs = LN(slots) @ M ----------------
__global__ __launch_bounds__(256) void k_pre(const float* __restrict__ slots, const float* __restrict__ g,
                                             const float* __restrict__ bbv, const float* __restrict__ M,
                                             float* __restrict__ qs){
  int row = blockIdx.x;      // 0..511 = b*8+i
  int t = threadIdx.x;
  __shared__ __align__(16) float sn[256];
  __shared__ float red[8];
  float v = slots[row*256 + t];
  float s = wredsum(v), ss = wredsum(v*v);
  int wid=t>>6, lane=t&63;
  if(lane==0){ red[wid]=s; red[4+wid]=ss; }
  __syncthreads();
  float S  = red[0]+red[1]+red[2]+red[3];
  float SS = red[4]+red[5]+red[6]+red[7];
  float m = S*(1.0f/256.0f);
  float r = rsqrtf(SS*(1.0f/256.0f) - m*m + 1e-5f);
  sn[t] = (v-m)*r*g[t]+bbv[t];
  __syncthreads();
  float acc=0.f;
#pragma unroll 4
  for(int e=0;e<256;e++) acc += sn[e]*M[e*256+t];
  qs[row*256+t]=acc;
}

// ---------------- pass1: dots + softmax(over slots) + eps -> w[b][j][8] ----------------
__global__ __launch_bounds__(256) void k_pass1(const __half* __restrict__ x, const float* __restrict__ qs,
                                               float* __restrict__ wbuf){
  int b = blockIdx.x>>4;                              // 16 blocks per batch
  size_t j = (size_t)blockIdx.x*256 + threadIdx.x;    // global row index (b*N + n)
  __shared__ __align__(16) float qt[256][8];          // qs transposed: [c][i]
  const float* qb = qs + b*2048;
  for(int e=threadIdx.x;e<2048;e+=256){ qt[e&255][e>>8]=qb[e]; }
  __syncthreads();
  const uint4* xr = (const uint4*)(x + j*DD);
  float pd[8]={0,0,0,0,0,0,0,0};
#pragma unroll 2
  for(int ch=0; ch<32; ch++){
    uint4 u = xr[ch];
    float2 f0=u2f2(u.x), f1=u2f2(u.y), f2=u2f2(u.z), f3=u2f2(u.w);
    float xv[8]={f0.x,f0.y,f1.x,f1.y,f2.x,f2.y,f3.x,f3.y};
    int c0=ch*8;
#pragma unroll
    for(int cc=0;cc<8;cc++){
      const float4* qp=(const float4*)&qt[c0+cc][0];
      float4 qa=qp[0], qc=qp[1];
      float xvv=xv[cc];
      pd[0]+=qa.x*xvv; pd[1]+=qa.y*xvv; pd[2]+=qa.z*xvv; pd[3]+=qa.w*xvv;
      pd[4]+=qc.x*xvv; pd[5]+=qc.y*xvv; pd[6]+=qc.z*xvv; pd[7]+=qc.w*xvv;
    }
  }
  float mx=pd[0];
#pragma unroll
  for(int i=1;i<8;i++) mx=fmaxf(mx,pd[i]);
  float ev[8]; float ssum=0.f;
#pragma unroll
  for(int i=0;i<8;i++){ ev[i]=__expf(pd[i]-mx); ssum+=ev[i]; }
  float inv=1.0f/ssum;
  float4 w0={ev[0]*inv+1e-5f, ev[1]*inv+1e-5f, ev[2]*inv+1e-5f, ev[3]*inv+1e-5f};
  float4 w1={ev[4]*inv+1e-5f, ev[5]*inv+1e-5f, ev[6]*inv+1e-5f, ev[7]*inv+1e-5f};
  float4* wp=(float4*)(wbuf + j*8);
  wp[0]=w0; wp[1]=w1;
}

// ---------------- pass2: partial agg[i][c] = sum_j w[i,j]*x[j,c], partial wsum ----------------
__global__ __launch_bounds__(256) void k_pass2(const __half* __restrict__ x, const float* __restrict__ wbuf,
                                               float* __restrict__ pagg){
  int b = blockIdx.x>>3, chnk = blockIdx.x&7;
  int jbase = chnk*512;
  __shared__ __align__(16) float wl[4096];         // 512 j * 8 i
  __shared__ __align__(16) float aggl[4][2048];
  __shared__ float wsl[4][8];
  const float* wsrc = wbuf + ((size_t)b*NN + jbase)*8;
  for(int e2=threadIdx.x;e2<4096;e2+=256) wl[e2]=wsrc[e2];
  __syncthreads();
  int wid=threadIdx.x>>6, lane=threadIdx.x&63;
  float acc[8][4];
#pragma unroll
  for(int i=0;i<8;i++){ acc[i][0]=0;acc[i][1]=0;acc[i][2]=0;acc[i][3]=0; }
  float ws[8]={0,0,0,0,0,0,0,0};
  const __half* xb = x + ((size_t)b*NN + jbase)*DD;
  for(int t2=0;t2<128;t2++){
    int jl = wid*128+t2;
    uint2 u = ((const uint2*)(xb + (size_t)jl*DD))[lane];
    float2 f01=u2f2(u.x), f23=u2f2(u.y);
    const float4* wp=(const float4*)&wl[jl*8];
    float4 wa=wp[0], wb_=wp[1];
    float wv[8]={wa.x,wa.y,wa.z,wa.w,wb_.x,wb_.y,wb_.z,wb_.w};
    float xv[4]={f01.x,f01.y,f23.x,f23.y};
#pragma unroll
    for(int i=0;i<8;i++){
      acc[i][0]+=wv[i]*xv[0]; acc[i][1]+=wv[i]*xv[1];
      acc[i][2]+=wv[i]*xv[2]; acc[i][3]+=wv[i]*xv[3];
      ws[i]+=wv[i];
    }
  }
#pragma unroll
  for(int i=0;i<8;i++){
    float4 st={acc[i][0],acc[i][1],acc[i][2],acc[i][3]};
    *((float4*)&aggl[wid][i*256 + lane*4])=st;
  }
  if(lane==0){
#pragma unroll
    for(int i=0;i<8;i++) wsl[wid][i]=ws[i];
  }
  __syncthreads();
  float* pb = pagg + (size_t)blockIdx.x*2064;
  for(int e2=threadIdx.x;e2<2048;e2+=256) pb[e2]=aggl[0][e2]+aggl[1][e2]+aggl[2][e2]+aggl[3][e2];
  if(threadIdx.x<8) pb[2048+threadIdx.x]=wsl[0][threadIdx.x]+wsl[1][threadIdx.x]+wsl[2][threadIdx.x]+wsl[3][threadIdx.x];
}

// ---------------- reduce partials + updates = (N/wsum)*agg @ Wv^T ----------------
__global__ __launch_bounds__(256) void k_upd(const float* __restrict__ pagg, const float* __restrict__ WvT,
                                             float* __restrict__ upd){
  int b=blockIdx.x, t=threadIdx.x;
  __shared__ float agg[2048];
  __shared__ float fac[8];
  for(int e=t;e<2048;e+=256){
    float s=0.f;
#pragma unroll
    for(int k=0;k<8;k++) s+=pagg[(size_t)(b*8+k)*2064+e];
    agg[e]=s;
  }
  if(t<8){
    float s=0.f;
#pragma unroll
    for(int k=0;k<8;k++) s+=pagg[(size_t)(b*8+k)*2064+2048+t];
    fac[t]=4096.0f/s;
  }
  __syncthreads();
  float a[8]={0,0,0,0,0,0,0,0};
#pragma unroll 2
  for(int c=0;c<256;c++){
    float wv=WvT[c*256+t];
#pragma unroll
    for(int i=0;i<8;i++) a[i]+=agg[i*256+c]*wv;
  }
#pragma unroll
  for(int i=0;i<8;i++) upd[(size_t)b*2048 + i*256 + t] = a[i]*fac[i];
}

// ---------------- GRU cell (PyTorch gate order r,z,n) ----------------
__global__ __launch_bounds__(512) void k_gru(const float* __restrict__ upd, const float* __restrict__ slots,
                                             const float* __restrict__ WihT, const float* __restrict__ WhhT,
                                             const float* __restrict__ bih, const float* __restrict__ bhh,
                                             float* __restrict__ h){
  int b=blockIdx.x, t=threadIdx.x;
  int d=t&255, ig=t>>8;                  // ig in {0,1}: rows ig*4..ig*4+3
  __shared__ float up[2048], sl[2048];
  for(int e=t;e<2048;e+=512){ up[e]=upd[(size_t)b*2048+e]; sl[e]=slots[(size_t)b*2048+e]; }
  __syncthreads();
  float ar[4]={0,0,0,0},az[4]={0,0,0,0},an[4]={0,0,0,0};
  float br_[4]={0,0,0,0},bz[4]={0,0,0,0},bn[4]={0,0,0,0};
  for(int c=0;c<256;c++){
    float wr=WihT[c*768+d], wz=WihT[c*768+256+d], wn=WihT[c*768+512+d];
    float vr=WhhT[c*768+d], vz=WhhT[c*768+256+d], vn=WhhT[c*768+512+d];
#pragma unroll
    for(int k=0;k<4;k++){
      float u=up[(ig*4+k)*256+c], s=sl[(ig*4+k)*256+c];
      ar[k]+=wr*u; az[k]+=wz*u; an[k]+=wn*u;
      br_[k]+=vr*s; bz[k]+=vz*s; bn[k]+=vn*s;
    }
  }
  float bir=bih[d], biz=bih[256+d], bin_=bih[512+d];
  float bhr=bhh[d], bhz=bhh[256+d], bhn=bhh[512+d];
#pragma unroll
  for(int k=0;k<4;k++){
    int i=ig*4+k;
    float r = 1.0f/(1.0f+__expf(-(ar[k]+bir+br_[k]+bhr)));
    float z = 1.0f/(1.0f+__expf(-(az[k]+biz+bz[k]+bhz)));
    float n = tanhf(an[k]+bin_ + r*(bn[k]+bhn));
    float hp = sl[i*256+d];
    h[(size_t)b*2048 + i*256 + d] = (1.0f-z)*n + z*hp;
  }
}

// ---------------- residual MLP with pre-norm ----------------
__global__ __launch_bounds__(512) void k_mlp(const float* __restrict__ h, const float* __restrict__ g,
                                             const float* __restrict__ bbv, const float* __restrict__ W1T,
                                             const float* __restrict__ b1, const float* __restrict__ W2T,
                                             const float* __restrict__ b2, float* __restrict__ slots){
  int b=blockIdx.x, t=threadIdx.x;
  __shared__ __align__(16) float hs[2048], ys[2048], z1s[8192];
  for(int e=t;e<2048;e+=512) hs[e]=h[(size_t)b*2048+e];
  __syncthreads();
  int wid=t>>6, lane=t&63;                 // wave wid handles row wid (8 waves)
  float4 hv = ((const float4*)&hs[wid*256])[lane];
  float s  = hv.x+hv.y+hv.z+hv.w;
  float ss = hv.x*hv.x+hv.y*hv.y+hv.z*hv.z+hv.w*hv.w;
  s=wredsum(s); ss=wredsum(ss);
  float m=s*(1.0f/256.0f);
  float r=rsqrtf(ss*(1.0f/256.0f)-m*m+1e-5f);
  float4 gv=((const float4*)g)[lane], bv=((const float4*)bbv)[lane];
  float4 y4={(hv.x-m)*r*gv.x+bv.x,(hv.y-m)*r*gv.y+bv.y,(hv.z-m)*r*gv.z+bv.z,(hv.w-m)*r*gv.w+bv.w};
  ((float4*)&ys[wid*256])[lane]=y4;
  __syncthreads();
  // z1 = leaky_relu(y @ W1^T + b1): thread covers cols t and t+512
  float a0[8]={0,0,0,0,0,0,0,0}, a1[8]={0,0,0,0,0,0,0,0};
  for(int c=0;c<256;c++){
    float w0=W1T[c*1024+t], w1=W1T[c*1024+512+t];
#pragma unroll
    for(int i=0;i<8;i++){ float yv=ys[i*256+c]; a0[i]+=w0*yv; a1[i]+=w1*yv; }
  }
  float bb0=b1[t], bb1=b1[512+t];
#pragma unroll
  for(int i=0;i<8;i++){
    float v0=a0[i]+bb0; v0 = v0>0.f? v0 : 0.01f*v0; z1s[i*1024+t]=v0;
    float v1=a1[i]+bb1; v1 = v1>0.f? v1 : 0.01f*v1; z1s[i*1024+512+t]=v1;
  }
  __syncthreads();
  // out = h + z1 @ W2^T + b2
  int d=t&255, ig=t>>8;
  float o[4]={0,0,0,0};
#pragma unroll 2
  for(int c=0;c<1024;c++){
    float w=W2T[c*256+d];
#pragma unroll
    for(int k=0;k<4;k++) o[k]+=z1s[(ig*4+k)*1024+c]*w;
  }
  float b2v=b2[d];
#pragma unroll
  for(int k=0;k<4;k++){
    int i=ig*4+k;
    slots[(size_t)b*2048 + i*256 + d] = hs[i*256+d] + o[k] + b2v;
  }
}

// ---------------- final copy (fp32 output — reference returns float32) ----------------
__global__ __launch_bounds__(256) void k_out(const float* __restrict__ slots, float* __restrict__ out){
  int e = blockIdx.x*256 + threadIdx.x;
  out[e] = slots[e];
}

extern "C" void kernel_launch(void* const* d_in, const int* in_sizes, int n_in,
                              void* d_out, int out_size, void* d_ws, size_t ws_size,
                              hipStream_t stream){
  const float* inputs=(const float*)d_in[0];
  const float* sinit =(const float*)d_in[1];
  const float* Wq =(const float*)d_in[2];
  const float* Wk =(const float*)d_in[3];
  const float* Wv =(const float*)d_in[4];
  const float* Wih=(const float*)d_in[5];
  const float* Whh=(const float*)d_in[6];
  const float* bih=(const float*)d_in[7];
  const float* bhh=(const float*)d_in[8];
  const float* lin_g=(const float*)d_in[9];
  const float* lin_b=(const float*)d_in[10];
  const float* ls_g=(const float*)d_in[11];
  const float* ls_b=(const float*)d_in[12];
  const float* lm_g=(const float*)d_in[13];
  const float* lm_b=(const float*)d_in[14];
  const float* W1=(const float*)d_in[15];
  const float* b1=(const float*)d_in[16];
  const float* W2=(const float*)d_in[17];
  const float* b2=(const float*)d_in[18];

  char* w=(char*)d_ws;
  __half* x   =(__half*)w; w += (size_t)BB*NN*DD*2;         // 134.2 MB
  float* wbuf =(float*)w;  w += (size_t)BB*NN*NSL*4;        //   8.4 MB
  float* qs   =(float*)w;  w += 512*256*4;
  float* M    =(float*)w;  w += 256*256*4;
  float* WihT =(float*)w;  w += 768*256*4;
  float* WhhT =(float*)w;  w += 768*256*4;
  float* W1T  =(float*)w;  w += 1024*256*4;
  float* W2T  =(float*)w;  w += 1024*256*4;
  float* WvT  =(float*)w;  w += 256*256*4;
  float* slots=(float*)w;  w += 512*256*4;
  float* upd  =(float*)w;  w += 512*256*4;
  float* hb   =(float*)w;  w += 512*256*4;
  float* pagg =(float*)w;  w += (size_t)512*2064*4;

  hipLaunchKernelGGL(k_prep, dim3(1088), dim3(256), 0, stream,
                     Wih,Whh,W1,W2,Wv,sinit, WihT,WhhT,W1T,W2T,WvT,slots);
  hipLaunchKernelGGL(k_M,    dim3(256),  dim3(256), 0, stream, Wq, Wk, M);
  hipLaunchKernelGGL(k_ln_x, dim3(65536),dim3(256), 0, stream, inputs, lin_g, lin_b, x);
  for(int it=0; it<NITER; ++it){
    hipLaunchKernelGGL(k_pre,   dim3(512), dim3(256), 0, stream, slots, ls_g, ls_b, M, qs);
    hipLaunchKernelGGL(k_pass1, dim3(1024),dim3(256), 0, stream, x, qs, wbuf);
    hipLaunchKernelGGL(k_pass2, dim3(512), dim3(256), 0, stream, x, wbuf, pagg);
    hipLaunchKernelGGL(k_upd,   dim3(64),  dim3(256), 0, stream, pagg, WvT, upd);
    hipLaunchKernelGGL(k_gru,   dim3(64),  dim3(512), 0, stream, upd, slots, WihT, WhhT, bih, bhh, hb);
    hipLaunchKernelGGL(k_mlp,   dim3(64),  dim3(512), 0, stream, hb, lm_g, lm_b, W1T, b1, W2T, b2, slots);
  }
  hipLaunchKernelGGL(k_out, dim3(512), dim3(256), 0, stream, slots, (float*)d_out);
}

// Round 3
// 691.580 us; speedup vs baseline: 1.9449x; 1.9449x over previous
//
#include <hip/hip_runtime.h>
#include <hip/hip_fp16.h>
#include <hip/hip_bf16.h>

// SlotAttention restructured:
//  dots = qs . x   with qs = LN(slots) @ (scale * Wq^T Wk)   (K never materialized)
//  updates = (N/wsum) * (sum_j w_j x_j) @ Wv^T               (V never materialized)
// x = LN(inputs) stored once as fp16. All accumulation fp32. Output fp32.
// R2: tail GEMMs (GRU/MLP) were latency-bound (64 blocks, 2 loads in flight,
// 430 cyc/iter). Split into wide kernels, unroll 8, grids 128-512.

#define BB 64
#define NN 4096
#define DD 256
#define NSL 8
#define NITER 3

__device__ __forceinline__ float wredsum(float v){
#pragma unroll
  for(int m=32;m;m>>=1) v += __shfl_xor(v, m, 64);
  return v;
}
__device__ __forceinline__ float2 u2f2(unsigned u){ __half2 h; __builtin_memcpy(&h,&u,4); return __half22float2(h); }
__device__ __forceinline__ float sigm(float v){ return 1.0f/(1.0f+__expf(-v)); }

// ---------------- prep: weight transposes + slots broadcast init ----------------
__global__ __launch_bounds__(256) void k_prep(
    const float* __restrict__ Wih, const float* __restrict__ Whh,
    const float* __restrict__ W1,  const float* __restrict__ W2,
    const float* __restrict__ Wv,  const float* __restrict__ sinit,
    float* __restrict__ WihT, float* __restrict__ WhhT,
    float* __restrict__ W1T,  float* __restrict__ W2T,
    float* __restrict__ WvT,  float* __restrict__ slots){
  for(int idx = blockIdx.x*256 + threadIdx.x; idx < 1114112; idx += gridDim.x*256){
    if(idx < 196608){ int d=idx>>8, c=idx&255; WihT[c*768+d] = Wih[idx]; }
    else if(idx < 393216){ int k=idx-196608; int d=k>>8,  c=k&255;  WhhT[c*768+d]  = Whh[k]; }
    else if(idx < 655360){ int k=idx-393216; int d=k>>8,  c=k&255;  W1T[c*1024+d]  = W1[k]; }   // W1 [1024][256]
    else if(idx < 917504){ int k=idx-655360; int d=k>>10, c=k&1023; W2T[c*256+d]   = W2[k]; }   // W2 [256][1024]
    else if(idx < 983040){ int k=idx-917504; int d=k>>8,  c=k&255;  WvT[c*256+d]   = Wv[k]; }
    else { int k=idx-983040; slots[k] = sinit[k&2047]; }                                        // broadcast over b
  }
}

// ---------------- M = scale * Wq^T @ Wk  (M[e][c]) ----------------
__global__ __launch_bounds__(256) void k_M(const float* __restrict__ Wq, const float* __restrict__ Wk,
                                           float* __restrict__ M){
  int e = blockIdx.x, c = threadIdx.x;
  float acc = 0.f;
#pragma unroll 8
  for(int d=0; d<256; d++) acc += Wq[d*256+e]*Wk[d*256+c];
  M[e*256+c] = acc * 0.0625f;  // 256^-0.5
}

// ---------------- x = LN(inputs) -> fp16 ----------------
__global__ __launch_bounds__(256) void k_ln_x(const float* __restrict__ in, const float* __restrict__ g,
                                              const float* __restrict__ bbv, __half* __restrict__ x){
  int row  = blockIdx.x*4 + (threadIdx.x>>6);
  int lane = threadIdx.x&63;
  const float4 v = ((const float4*)(in + (size_t)row*DD))[lane];
  float s  = v.x+v.y+v.z+v.w;
  float ss = v.x*v.x+v.y*v.y+v.z*v.z+v.w*v.w;
  s = wredsum(s); ss = wredsum(ss);
  float m = s*(1.0f/256.0f);
  float r = rsqrtf(ss*(1.0f/256.0f) - m*m + 1e-5f);
  float4 gv = ((const float4*)g)[lane];
  float4 bv = ((const float4*)bbv)[lane];
  float y0=(v.x-m)*r*gv.x+bv.x, y1=(v.y-m)*r*gv.y+bv.y;
  float y2=(v.z-m)*r*gv.z+bv.z, y3=(v.w-m)*r*gv.w+bv.w;
  __half2 h0=__floats2half2_rn(y0,y1), h1=__floats2half2_rn(y2,y3);
  uint2 u; __builtin_memcpy(&u.x,&h0,4); __builtin_memcpy(&u.y,&h1,4);
  ((uint2*)(x + (size_t)row*DD))[lane] = u;
}

// ---------------- per-iter: qs = LN(slots) @ M ----------------
__global__ __launch_bounds__(256) void k_pre(const float* __restrict__ slots, const float* __restrict__ g,
                                             const float* __restrict__ bbv, const float* __restrict__ M,
                                             float* __restrict__ qs){
  int row = blockIdx.x;      // 0..511 = b*8+i
  int t = threadIdx.x;
  __shared__ __align__(16) float sn[256];
  __shared__ float red[8];
  float v = slots[row*256 + t];
  float s = wredsum(v), ss = wredsum(v*v);
  int wid=t>>6, lane=t&63;
  if(lane==0){ red[wid]=s; red[4+wid]=ss; }
  __syncthreads();
  float S  = red[0]+red[1]+red[2]+red[3];
  float SS = red[4]+red[5]+red[6]+red[7];
  float m = S*(1.0f/256.0f);
  float r = rsqrtf(SS*(1.0f/256.0f) - m*m + 1e-5f);
  sn[t] = (v-m)*r*g[t]+bbv[t];
  __syncthreads();
  float acc=0.f;
#pragma unroll 8
  for(int e=0;e<256;e++) acc += sn[e]*M[e*256+t];
  qs[row*256+t]=acc;
}

// ---------------- pass1: dots + softmax(over slots) + eps -> w[b][j][8] ----------------
__global__ __launch_bounds__(256) void k_pass1(const __half* __restrict__ x, const float* __restrict__ qs,
                                               float* __restrict__ wbuf){
  int b = blockIdx.x>>4;                              // 16 blocks per batch
  size_t j = (size_t)blockIdx.x*256 + threadIdx.x;    // global row index (b*N + n)
  __shared__ __align__(16) float qt[256][8];          // qs transposed: [c][i]
  const float* qb = qs + b*2048;
  for(int e=threadIdx.x;e<2048;e+=256){ qt[e&255][e>>8]=qb[e]; }
  __syncthreads();
  const uint4* xr = (const uint4*)(x + j*DD);
  float pd[8]={0,0,0,0,0,0,0,0};
#pragma unroll 2
  for(int ch=0; ch<32; ch++){
    uint4 u = xr[ch];
    float2 f0=u2f2(u.x), f1=u2f2(u.y), f2=u2f2(u.z), f3=u2f2(u.w);
    float xv[8]={f0.x,f0.y,f1.x,f1.y,f2.x,f2.y,f3.x,f3.y};
    int c0=ch*8;
#pragma unroll
    for(int cc=0;cc<8;cc++){
      const float4* qp=(const float4*)&qt[c0+cc][0];
      float4 qa=qp[0], qc=qp[1];
      float xvv=xv[cc];
      pd[0]+=qa.x*xvv; pd[1]+=qa.y*xvv; pd[2]+=qa.z*xvv; pd[3]+=qa.w*xvv;
      pd[4]+=qc.x*xvv; pd[5]+=qc.y*xvv; pd[6]+=qc.z*xvv; pd[7]+=qc.w*xvv;
    }
  }
  float mx=pd[0];
#pragma unroll
  for(int i=1;i<8;i++) mx=fmaxf(mx,pd[i]);
  float ev[8]; float ssum=0.f;
#pragma unroll
  for(int i=0;i<8;i++){ ev[i]=__expf(pd[i]-mx); ssum+=ev[i]; }
  float inv=1.0f/ssum;
  float4 w0={ev[0]*inv+1e-5f, ev[1]*inv+1e-5f, ev[2]*inv+1e-5f, ev[3]*inv+1e-5f};
  float4 w1={ev[4]*inv+1e-5f, ev[5]*inv+1e-5f, ev[6]*inv+1e-5f, ev[7]*inv+1e-5f};
  float4* wp=(float4*)(wbuf + j*8);
  wp[0]=w0; wp[1]=w1;
}

// ---------------- pass2: partial agg[i][c] = sum_j w[i,j]*x[j,c], partial wsum ----------------
__global__ __launch_bounds__(256) void k_pass2(const __half* __restrict__ x, const float* __restrict__ wbuf,
                                               float* __restrict__ pagg){
  int b = blockIdx.x>>3, chnk = blockIdx.x&7;
  int jbase = chnk*512;
  __shared__ __align__(16) float wl[4096];         // 512 j * 8 i
  __shared__ __align__(16) float aggl[4][2048];
  __shared__ float wsl[4][8];
  const float* wsrc = wbuf + ((size_t)b*NN + jbase)*8;
  for(int e2=threadIdx.x;e2<4096;e2+=256) wl[e2]=wsrc[e2];
  __syncthreads();
  int wid=threadIdx.x>>6, lane=threadIdx.x&63;
  float acc[8][4];
#pragma unroll
  for(int i=0;i<8;i++){ acc[i][0]=0;acc[i][1]=0;acc[i][2]=0;acc[i][3]=0; }
  float ws[8]={0,0,0,0,0,0,0,0};
  const __half* xb = x + ((size_t)b*NN + jbase)*DD;
  for(int t2=0;t2<128;t2++){
    int jl = wid*128+t2;
    uint2 u = ((const uint2*)(xb + (size_t)jl*DD))[lane];
    float2 f01=u2f2(u.x), f23=u2f2(u.y);
    const float4* wp=(const float4*)&wl[jl*8];
    float4 wa=wp[0], wb_=wp[1];
    float wv[8]={wa.x,wa.y,wa.z,wa.w,wb_.x,wb_.y,wb_.z,wb_.w};
    float xv[4]={f01.x,f01.y,f23.x,f23.y};
#pragma unroll
    for(int i=0;i<8;i++){
      acc[i][0]+=wv[i]*xv[0]; acc[i][1]+=wv[i]*xv[1];
      acc[i][2]+=wv[i]*xv[2]; acc[i][3]+=wv[i]*xv[3];
      ws[i]+=wv[i];
    }
  }
#pragma unroll
  for(int i=0;i<8;i++){
    float4 st={acc[i][0],acc[i][1],acc[i][2],acc[i][3]};
    *((float4*)&aggl[wid][i*256 + lane*4])=st;
  }
  if(lane==0){
#pragma unroll
    for(int i=0;i<8;i++) wsl[wid][i]=ws[i];
  }
  __syncthreads();
  float* pb = pagg + (size_t)blockIdx.x*2064;
  for(int e2=threadIdx.x;e2<2048;e2+=256) pb[e2]=aggl[0][e2]+aggl[1][e2]+aggl[2][e2]+aggl[3][e2];
  if(threadIdx.x<8) pb[2048+threadIdx.x]=wsl[0][threadIdx.x]+wsl[1][threadIdx.x]+wsl[2][threadIdx.x]+wsl[3][threadIdx.x];
}

// ---------------- reduce partials + updates = (N/wsum)*agg @ Wv^T ----------------
__global__ __launch_bounds__(256) void k_upd(const float* __restrict__ pagg, const float* __restrict__ WvT,
                                             float* __restrict__ upd){
  int b=blockIdx.x, t=threadIdx.x;
  __shared__ float agg[2048];
  __shared__ float fac[8];
  for(int e=t;e<2048;e+=256){
    float s=0.f;
#pragma unroll
    for(int k=0;k<8;k++) s+=pagg[(size_t)(b*8+k)*2064+e];
    agg[e]=s;
  }
  if(t<8){
    float s=0.f;
#pragma unroll
    for(int k=0;k<8;k++) s+=pagg[(size_t)(b*8+k)*2064+2048+t];
    fac[t]=4096.0f/s;
  }
  __syncthreads();
  float a[8]={0,0,0,0,0,0,0,0};
#pragma unroll 8
  for(int c=0;c<256;c++){
    float wv=WvT[c*256+t];
#pragma unroll
    for(int i=0;i<8;i++) a[i]+=agg[i*256+c]*wv;
  }
#pragma unroll
  for(int i=0;i<8;i++) upd[(size_t)b*2048 + i*256 + t] = a[i]*fac[i];
}

// ---------------- GRU gate GEMMs: gates[row][0:768]=upd@WihT+bih, [768:1536]=slots@WhhT+bhh ----------------
__global__ __launch_bounds__(256) void k_gates(const float* __restrict__ upd, const float* __restrict__ slots,
                                               const float* __restrict__ WihT, const float* __restrict__ WhhT,
                                               const float* __restrict__ bih, const float* __restrict__ bhh,
                                               float* __restrict__ gates){
  int blk=blockIdx.x;                 // 0..383
  int b=blk/6, chunk=blk%6;
  int t=threadIdx.x;
  bool isH = chunk>=3;
  int col = (chunk%3)*256 + t;        // 0..767
  const float* src  = isH ? (slots + (size_t)b*2048) : (upd + (size_t)b*2048);
  const float* WT   = isH ? WhhT : WihT;
  const float* bias = isH ? bhh  : bih;
  __shared__ float in[2048];
  for(int e=t;e<2048;e+=256) in[e]=src[e];
  __syncthreads();
  float a[8]={0,0,0,0,0,0,0,0};
#pragma unroll 8
  for(int c=0;c<256;c++){
    float w=WT[c*768+col];
#pragma unroll
    for(int i=0;i<8;i++) a[i]+=in[i*256+c]*w;
  }
  float bv=bias[col];
  size_t base=(size_t)(b*8)*1536 + (isH?768:0) + col;
#pragma unroll
  for(int i=0;i<8;i++) gates[base + (size_t)i*1536] = a[i]+bv;
}

// ---------------- GRU nonlinearity + MLP pre-norm (fused) ----------------
__global__ __launch_bounds__(256) void k_gru_ln(const float* __restrict__ gates, const float* __restrict__ slots,
                                                const float* __restrict__ g, const float* __restrict__ bbv,
                                                float* __restrict__ h, float* __restrict__ ys){
  int row=blockIdx.x, t=threadIdx.x;
  const float* gr = gates + (size_t)row*1536;
  float gir=gr[t], giz=gr[256+t], gin=gr[512+t];
  float ghr=gr[768+t], ghz=gr[1024+t], ghn=gr[1280+t];
  float hp = slots[(size_t)row*256+t];
  float r = sigm(gir+ghr);
  float z = sigm(giz+ghz);
  float n = tanhf(gin + r*ghn);
  float hv = (1.0f-z)*n + z*hp;
  h[(size_t)row*256+t] = hv;
  // LayerNorm(hv) across the row
  float s=wredsum(hv), ss=wredsum(hv*hv);
  __shared__ float red[8];
  int wid=t>>6, lane=t&63;
  if(lane==0){ red[wid]=s; red[4+wid]=ss; }
  __syncthreads();
  float S=red[0]+red[1]+red[2]+red[3];
  float SS=red[4]+red[5]+red[6]+red[7];
  float m=S*(1.0f/256.0f);
  float rs=rsqrtf(SS*(1.0f/256.0f)-m*m+1e-5f);
  ys[(size_t)row*256+t]=(hv-m)*rs*g[t]+bbv[t];
}

// ---------------- MLP up-proj: z1 = leaky_relu(ys @ W1^T + b1)  [512,1024] ----------------
__global__ __launch_bounds__(256) void k_mlp1(const float* __restrict__ ys, const float* __restrict__ W1T,
                                              const float* __restrict__ b1, float* __restrict__ z1){
  int blk=blockIdx.x;                 // 0..255
  int b=blk>>2, chunk=blk&3;
  int t=threadIdx.x;
  int col=chunk*256+t;                // 0..1023
  __shared__ float in[2048];
  const float* src = ys + (size_t)b*2048;
  for(int e=t;e<2048;e+=256) in[e]=src[e];
  __syncthreads();
  float a[8]={0,0,0,0,0,0,0,0};
#pragma unroll 8
  for(int c=0;c<256;c++){
    float w=W1T[c*1024+col];
#pragma unroll
    for(int i=0;i<8;i++) a[i]+=in[i*256+c]*w;
  }
  float bv=b1[col];
#pragma unroll
  for(int i=0;i<8;i++){
    float v=a[i]+bv; v = v>0.f ? v : 0.01f*v;
    z1[(size_t)(b*8+i)*1024+col]=v;
  }
}

// ---------------- MLP down-proj + residual: out = h + z1 @ W2^T + b2 ----------------
__global__ __launch_bounds__(256) void k_mlp2(const float* __restrict__ z1, const float* __restrict__ h,
                                              const float* __restrict__ W2T, const float* __restrict__ b2,
                                              float* __restrict__ out){
  int blk=blockIdx.x;                 // 0..127
  int b=blk>>1, half=blk&1;
  int t=threadIdx.x;
  int r0=b*8+half*4;
  __shared__ float zl[4096];          // 4 rows x 1024
  const float* src = z1 + (size_t)r0*1024;
  for(int e=t;e<4096;e+=256) zl[e]=src[e];
  __syncthreads();
  float a[4]={0,0,0,0};
#pragma unroll 8
  for(int c=0;c<1024;c++){
    float w=W2T[c*256+t];
#pragma unroll
    for(int k=0;k<4;k++) a[k]+=zl[k*1024+c]*w;
  }
  float bv=b2[t];
#pragma unroll
  for(int k=0;k<4;k++){
    size_t o=(size_t)(r0+k)*256+t;
    out[o]=h[o]+a[k]+bv;
  }
}

extern "C" void kernel_launch(void* const* d_in, const int* in_sizes, int n_in,
                              void* d_out, int out_size, void* d_ws, size_t ws_size,
                              hipStream_t stream){
  const float* inputs=(const float*)d_in[0];
  const float* sinit =(const float*)d_in[1];
  const float* Wq =(const float*)d_in[2];
  const float* Wk =(const float*)d_in[3];
  const float* Wv =(const float*)d_in[4];
  const float* Wih=(const float*)d_in[5];
  const float* Whh=(const float*)d_in[6];
  const float* bih=(const float*)d_in[7];
  const float* bhh=(const float*)d_in[8];
  const float* lin_g=(const float*)d_in[9];
  const float* lin_b=(const float*)d_in[10];
  const float* ls_g=(const float*)d_in[11];
  const float* ls_b=(const float*)d_in[12];
  const float* lm_g=(const float*)d_in[13];
  const float* lm_b=(const float*)d_in[14];
  const float* W1=(const float*)d_in[15];
  const float* b1=(const float*)d_in[16];
  const float* W2=(const float*)d_in[17];
  const float* b2=(const float*)d_in[18];

  char* w=(char*)d_ws;
  __half* x   =(__half*)w; w += (size_t)BB*NN*DD*2;         // 134.2 MB
  float* wbuf =(float*)w;  w += (size_t)BB*NN*NSL*4;        //   8.4 MB
  float* qs   =(float*)w;  w += 512*256*4;
  float* M    =(float*)w;  w += 256*256*4;
  float* WihT =(float*)w;  w += 768*256*4;
  float* WhhT =(float*)w;  w += 768*256*4;
  float* W1T  =(float*)w;  w += 1024*256*4;
  float* W2T  =(float*)w;  w += 1024*256*4;
  float* WvT  =(float*)w;  w += 256*256*4;
  float* slots=(float*)w;  w += 512*256*4;
  float* upd  =(float*)w;  w += 512*256*4;
  float* hb   =(float*)w;  w += 512*256*4;
  float* ysb  =(float*)w;  w += 512*256*4;
  float* gates=(float*)w;  w += (size_t)512*1536*4;
  float* z1   =(float*)w;  w += (size_t)512*1024*4;
  float* pagg =(float*)w;  w += (size_t)512*2064*4;

  hipLaunchKernelGGL(k_prep, dim3(1088), dim3(256), 0, stream,
                     Wih,Whh,W1,W2,Wv,sinit, WihT,WhhT,W1T,W2T,WvT,slots);
  hipLaunchKernelGGL(k_M,    dim3(256),  dim3(256), 0, stream, Wq, Wk, M);
  hipLaunchKernelGGL(k_ln_x, dim3(65536),dim3(256), 0, stream, inputs, lin_g, lin_b, x);
  for(int it=0; it<NITER; ++it){
    float* dst = (it==NITER-1) ? (float*)d_out : slots;
    hipLaunchKernelGGL(k_pre,    dim3(512), dim3(256), 0, stream, slots, ls_g, ls_b, M, qs);
    hipLaunchKernelGGL(k_pass1,  dim3(1024),dim3(256), 0, stream, x, qs, wbuf);
    hipLaunchKernelGGL(k_pass2,  dim3(512), dim3(256), 0, stream, x, wbuf, pagg);
    hipLaunchKernelGGL(k_upd,    dim3(64),  dim3(256), 0, stream, pagg, WvT, upd);
    hipLaunchKernelGGL(k_gates,  dim3(384), dim3(256), 0, stream, upd, slots, WihT, WhhT, bih, bhh, gates);
    hipLaunchKernelGGL(k_gru_ln, dim3(512), dim3(256), 0, stream, gates, slots, lm_g, lm_b, hb, ysb);
    hipLaunchKernelGGL(k_mlp1,   dim3(256), dim3(256), 0, stream, ysb, W1T, b1, z1);
    hipLaunchKernelGGL(k_mlp2,   dim3(128), dim3(256), 0, stream, z1, hb, W2T, b2, dst);
  }
}